// Round 5
// baseline (664.413 us; speedup 1.0000x reference)
//
#include <hip/hip_runtime.h>

typedef _Float16 half8 __attribute__((ext_vector_type(8)));
typedef float f32x4 __attribute__((ext_vector_type(4)));

#define HDIM 768
#define NTOK 32768
#define BK 32
#define NKT (HDIM / BK)   // 24

// ---- workspace layout (bytes) ----
static constexpr size_t WX_OFF   = 0;                   // int8  [NTOK*HDIM] = 25165824
static constexpr size_t WINT_OFF = 25165824;            // f16   [HDIM*HDIM] = 1179648 B
static constexpr size_t RS1_OFF  = WINT_OFF + 1179648;  // double[768]
static constexpr size_t RS2_OFF  = RS1_OFF + 6144;      // double[768]
static constexpr size_t BS_OFF   = RS2_OFF + 6144;      // float [768] bias_scale
static constexpr size_t BINT_OFF = BS_OFF + 3072;       // int   [768] b_int
static constexpr size_t LNBI_OFF = BINT_OFF + 3072;     // int   [768] LN bias_int
static constexpr size_t SFO_OFF  = LNBI_OFF + 3072;     // float [768] sf_out
static constexpr size_t SC_OFF   = SFO_OFF + 3072;      // scalars: [0]min1 [1]max1 [2]min2 [3]max2 [4]shift [5]s [6]s2
static constexpr size_t RSM1_OFF = SC_OFF + 64;         // double rs_m1
static constexpr size_t MEAN_OFF = RSM1_OFF + 64;       // int  [NTOK] per-row mean
static constexpr size_t FACT_OFF = MEAN_OFF + 131072;   // ll   [NTOK] per-row factor

// sortable-uint encoding of float for atomic min/max
__device__ __forceinline__ unsigned fenc(float f) {
    unsigned u = __float_as_uint(f);
    return (u >> 31) ? ~u : (u | 0x80000000u);
}
__device__ __forceinline__ float fdec(unsigned e) {
    unsigned u = (e >> 31) ? (e & 0x7fffffffu) : ~e;
    return __uint_as_float(u);
}

// ============ K0: weight quantization + per-channel tables + scalar init ============
__global__ __launch_bounds__(256) void k0_prep(const float* __restrict__ W,
                                               const float* __restrict__ bias,
                                               const float* __restrict__ ln_w,
                                               const float* __restrict__ ln_b,
                                               const float* __restrict__ phsf,
                                               char* __restrict__ ws) {
    int o = blockIdx.x, tid = threadIdx.x;
    __shared__ float red[256];
    __shared__ float fc_sh;
    float m = 0.f;
    for (int j = tid; j < HDIM; j += 256) m = fmaxf(m, fabsf(W[(size_t)o * HDIM + j]));
    red[tid] = m;
    __syncthreads();
    for (int s = 128; s; s >>= 1) { if (tid < s) red[tid] = fmaxf(red[tid], red[tid + s]); __syncthreads(); }
    if (tid == 0) {
        float fc = fmaxf(red[0], 1e-8f) / 127.0f;     // _sym_scale(8,...)
        float hsf = *phsf;
        float bs = fc * hsf;
        fc_sh = fc;
        ((float*)(ws + BS_OFF))[o] = bs;
        ((int*)(ws + BINT_OFF))[o] = (int)rintf(bias[o] / bs);   // _sym_quant(bias,32)
        float sf = sqrtf(768.0f) / 1073741824.0f;                // sqrt(H)/2^30
        float lw = ln_w[o], lb = ln_b[o];
        ((int*)(ws + LNBI_OFF))[o] = (int)floorf((lb / lw) / sf);
        ((float*)(ws + SFO_OFF))[o] = sf * lw;
    }
    __syncthreads();
    float fc = fc_sh;
    _Float16* w16 = (_Float16*)(ws + WINT_OFF);
    for (int j = tid; j < HDIM; j += 256) {
        float q = rintf(W[(size_t)o * HDIM + j] / fc);
        q = fminf(fmaxf(q, -127.f), 126.f);           // clip [-n, n-1]
        w16[(size_t)o * HDIM + j] = (_Float16)q;
    }
    if (blockIdx.x == 0 && tid < 8) {
        unsigned* sc = (unsigned*)(ws + SC_OFF);
        unsigned v = 0u;
        if (tid == 0 || tid == 2) v = 0xFFFFFFFFu;    // min slots
        sc[tid] = v;                                   // max slots + shift -> 0
    }
}

// ============ K1: barrier-free register GEMM (exact, f16 MFMA) ============
// Each wave: 64 rows x 32 cols. Block = 4 waves sharing the same 64 A-rows
// (L1 reuse), covering 128 cols. No LDS, no __syncthreads in the K-loop.
// A: f32 global -> inline f16 convert (RTNE cvt exact for int-valued |x|<=128,
// abs err ~8e-6 << 0.03125 half-spacing). B: f16 from L2-resident w16.
// XCD remap: 6 N-blocks of one M-chunk pinned to one XCD -> A HBM-fetched once.
__global__ __launch_bounds__(256) void k1_gemm(const float* __restrict__ hs_in,
                                               const float* __restrict__ inp,
                                               const float* __restrict__ phsf,
                                               const float* __restrict__ pisf,
                                               char* __restrict__ ws,
                                               int* __restrict__ accOut) {
    __shared__ float rmn[4], rmx[4];
    int tid = threadIdx.x, lane = tid & 63, wave = tid >> 6;
    int wrow = lane & 15, wkg = lane >> 4;
    int bid = blockIdx.x;
    int xcd = bid & 7, slot = bid >> 3;       // 8 XCDs x 384 slots
    int mchunk = xcd * 64 + slot / 6;         // 512 M-chunks, 64 per XCD
    int nslab = slot % 6;
    int t0 = mchunk * 64;
    int ob = nslab * 128 + wave * 32;
    float inv_hsf = 1.0f / *phsf;
    float inv_isf = 1.0f / *pisf;
    const _Float16* w16 = (const _Float16*)(ws + WINT_OFF);

    const float* aptr[4];
    #pragma unroll
    for (int mf = 0; mf < 4; ++mf) aptr[mf] = hs_in + (size_t)(t0 + mf * 16 + wrow) * HDIM + wkg * 8;
    const _Float16* bptr[2];
    #pragma unroll
    for (int nf = 0; nf < 2; ++nf) bptr[nf] = w16 + (size_t)(ob + nf * 16 + wrow) * HDIM + wkg * 8;

    f32x4 acc[4][2] = {};
    float4 a0[4], a1[4];
    half8 bv[2];
    #pragma unroll
    for (int mf = 0; mf < 4; ++mf) { a0[mf] = *(const float4*)(aptr[mf]); a1[mf] = *(const float4*)(aptr[mf] + 4); }
    #pragma unroll
    for (int nf = 0; nf < 2; ++nf) bv[nf] = *(const half8*)(bptr[nf]);

    for (int kt = 0; kt < NKT; ++kt) {
        // 1) convert prev-loaded A (frees a0/a1 for reuse)
        half8 af[4];
        #pragma unroll
        for (int mf = 0; mf < 4; ++mf) {
            half8 h;
            h[0] = (_Float16)(a0[mf].x * inv_hsf); h[1] = (_Float16)(a0[mf].y * inv_hsf);
            h[2] = (_Float16)(a0[mf].z * inv_hsf); h[3] = (_Float16)(a0[mf].w * inv_hsf);
            h[4] = (_Float16)(a1[mf].x * inv_hsf); h[5] = (_Float16)(a1[mf].y * inv_hsf);
            h[6] = (_Float16)(a1[mf].z * inv_hsf); h[7] = (_Float16)(a1[mf].w * inv_hsf);
            af[mf] = h;
        }
        // 2) issue next iter's loads (in flight across the MFMAs)
        half8 nbv[2];
        if (kt < NKT - 1) {
            int off = (kt + 1) * BK;
            #pragma unroll
            for (int mf = 0; mf < 4; ++mf) {
                a0[mf] = *(const float4*)(aptr[mf] + off);
                a1[mf] = *(const float4*)(aptr[mf] + off + 4);
            }
            #pragma unroll
            for (int nf = 0; nf < 2; ++nf) nbv[nf] = *(const half8*)(bptr[nf] + off);
        }
        // 3) MFMAs
        #pragma unroll
        for (int mf = 0; mf < 4; ++mf)
            #pragma unroll
            for (int nf = 0; nf < 2; ++nf)
                acc[mf][nf] = __builtin_amdgcn_mfma_f32_16x16x32_f16(af[mf], bv[nf], acc[mf][nf], 0, 0, 0);
        if (kt < NKT - 1) { bv[0] = nbv[0]; bv[1] = nbv[1]; }
    }

    // epilogue: bias add, store acc (int32), x_act min/max, wx store
    const float* bscale = (const float*)(ws + BS_OFF);
    const int* bint = (const int*)(ws + BINT_OFF);
    char* wx = (char*)(ws + WX_OFF);
    float lmn = 3.402823466e38f, lmx = -3.402823466e38f;
    #pragma unroll
    for (int mf = 0; mf < 4; ++mf)
        #pragma unroll
        for (int nf = 0; nf < 2; ++nf) {
            int o = ob + nf * 16 + wrow;
            int bi = bint[o];
            float bsc = bscale[o];
            #pragma unroll
            for (int r = 0; r < 4; ++r) {
                int t = t0 + mf * 16 + wkg * 4 + r;
                int a = (int)acc[mf][nf][r] + bi;
                size_t idx = (size_t)t * HDIM + o;
                accOut[idx] = a;
                float xin = inp[idx];
                float xa = (float)a * bsc + xin;
                lmn = fminf(lmn, xa);
                lmx = fmaxf(lmx, xa);
                wx[idx] = (char)rintf(xin * inv_isf);
            }
        }
    #pragma unroll
    for (int off = 32; off; off >>= 1) {
        lmn = fminf(lmn, __shfl_down(lmn, off));
        lmx = fmaxf(lmx, __shfl_down(lmx, off));
    }
    if (lane == 0) { rmn[wave] = lmn; rmx[wave] = lmx; }
    __syncthreads();
    if (tid == 0) {
        float mn = fminf(fminf(rmn[0], rmn[1]), fminf(rmn[2], rmn[3]));
        float mx = fmaxf(fmaxf(rmx[0], rmx[1]), fmaxf(rmx[2], rmx[3]));
        volatile unsigned* sc = (volatile unsigned*)(ws + SC_OFF);
        unsigned emn = fenc(mn), emx = fenc(mx);
        if (emn < sc[0]) atomicMin((unsigned*)&sc[0], emn);   // guarded, monotone
        if (emx > sc[1]) atomicMax((unsigned*)&sc[1], emx);
    }
}

// ============ K2: finalize ln_in_scale s + frexp tables ============
__global__ __launch_bounds__(256) void k2_scale1(const float* __restrict__ pisf, char* __restrict__ ws) {
    __shared__ float s_sh;
    unsigned* sc = (unsigned*)(ws + SC_OFF);
    if (threadIdx.x == 0) {
        float mn = fdec(sc[0]), mx = fdec(sc[1]);
        float s = fmaxf(fmaxf(fabsf(mn), fabsf(mx)), 1e-8f) / 2097151.0f;  // n = 2^21-1
        ((float*)sc)[5] = s;
        s_sh = s;
        double r = (double)(*pisf) / (double)s;
        int ex; double mant = frexp(r, &ex);
        double m1 = floor(mant * 2147483648.0 + 0.5);
        ((double*)(ws + RSM1_OFF))[0] = m1 * exp2((double)(ex - 31));
    }
    __syncthreads();
    float s = s_sh;
    const float* bs = (const float*)(ws + BS_OFF);
    double* rs1 = (double*)(ws + RS1_OFF);
    for (int o = threadIdx.x; o < HDIM; o += 256) {
        double r = (double)bs[o] / (double)s;
        int ex; double mant = frexp(r, &ex);
        double m = floor(mant * 2147483648.0 + 0.5);
        rs1[o] = m * exp2((double)(ex - 31));
    }
}

// shared q-recompute: exact f64 single-rounding fixed-point requant
__device__ __forceinline__ void computeQ(const int4& a, int w4, int o0,
                                         const double* rs1, double rsm1, int* q) {
    int av[4] = {a.x, a.y, a.z, a.w};
    #pragma unroll
    for (int j = 0; j < 4; ++j) {
        double q1 = rint((double)av[j] * rs1[o0 + j]);
        int wxj = (int)(char)(w4 >> (8 * j));
        double qq = q1 + rint((double)wxj * rsm1);
        qq = fmin(fmax(qq, -2097152.0), 2097151.0);   // clip [-2^21, 2^21-1]
        q[j] = (int)qq;
    }
}

// ============ K3: wave-per-row stats ONLY (mean + shift); no q write ============
__global__ __launch_bounds__(256) void k3_rows(char* __restrict__ ws, const int* __restrict__ buf) {
    __shared__ int shs[4];
    int tid = threadIdx.x, lane = tid & 63, wave = tid >> 6;
    int row = blockIdx.x * 4 + wave;
    size_t base = (size_t)row * HDIM;
    const double* rs1 = (const double*)(ws + RS1_OFF);
    double rsm1 = *(const double*)(ws + RSM1_OFF);
    int q[12];
    int sum = 0;
    #pragma unroll
    for (int c = 0; c < 3; ++c) {
        int4 a = ((const int4*)(buf + base))[lane + 64 * c];
        int w4 = ((const int*)(ws + WX_OFF + base))[lane + 64 * c];
        computeQ(a, w4, (lane + 64 * c) * 4, rs1, rsm1, &q[c * 4]);
        sum += q[c * 4] + q[c * 4 + 1] + q[c * 4 + 2] + q[c * 4 + 3];
    }
    #pragma unroll
    for (int off = 32; off; off >>= 1) sum += __shfl_xor(sum, off);
    int mean = (int)rint((double)sum / 768.0);
    long long var0 = 0;
    #pragma unroll
    for (int k = 0; k < 12; ++k) { int y = q[k] - mean; var0 += (long long)y * (long long)y; }
    #pragma unroll
    for (int off = 32; off; off >>= 1) var0 += __shfl_xor(var0, off);
    if (lane == 0) {
        ((int*)(ws + MEAN_OFF))[row] = mean;
        double v = (double)(var0 < 1 ? 1LL : var0);
        shs[wave] = (int)ceil(0.5 * log2(v) - 16.0);   // ceil(log2(sqrt(v/2^32)))
    }
    __syncthreads();
    if (tid == 0) {
        int sr = max(max(shs[0], shs[1]), max(shs[2], shs[3]));
        if (sr > 0) {
            int* sp = (int*)(ws + SC_OFF) + 4;
            if (sr > *(volatile int*)sp) atomicMax(sp, sr);   // guarded, monotone, 1/block
        }
    }
}

// ============ K4: wave-per-row: recompute q, var@shift, factor, hs min/max ============
__global__ __launch_bounds__(256) void k4_rows(char* __restrict__ ws, const int* __restrict__ buf) {
    __shared__ float fmn[4], fmx[4];
    int tid = threadIdx.x, lane = tid & 63, wave = tid >> 6;
    int row = blockIdx.x * 4 + wave;
    size_t base = (size_t)row * HDIM;
    const double* rs1 = (const double*)(ws + RS1_OFF);
    double rsm1 = *(const double*)(ws + RSM1_OFF);
    int shift = *(((const int*)(ws + SC_OFF)) + 4);
    int mean = ((const int*)(ws + MEAN_OFF))[row];
    const int* lnbi = (const int*)(ws + LNBI_OFF);
    const float* sfo = (const float*)(ws + SFO_OFF);
    int q[12];
    #pragma unroll
    for (int c = 0; c < 3; ++c) {
        int4 a = ((const int4*)(buf + base))[lane + 64 * c];
        int w4 = ((const int*)(ws + WX_OFF + base))[lane + 64 * c];
        computeQ(a, w4, (lane + 64 * c) * 4, rs1, rsm1, &q[c * 4]);
    }
    long long var = 0;
    #pragma unroll
    for (int k = 0; k < 12; ++k) { int ysh = (q[k] - mean) >> shift; var += (long long)ysh * (long long)ysh; }
    #pragma unroll
    for (int off = 32; off; off >>= 1) var += __shfl_xor(var, off);
    double std_int = floor(sqrt((double)var)) * (double)(1LL << shift);
    if (std_int < 1.0) std_int = 1.0;
    long long factor = (long long)floor(2147483648.0 / std_int);
    if (lane == 0) ((long long*)(ws + FACT_OFF))[row] = factor;
    float lmn = 3.402823466e38f, lmx = -3.402823466e38f;
    #pragma unroll
    for (int c = 0; c < 3; ++c) {
        int o0 = (lane + 64 * c) * 4;
        #pragma unroll
        for (int j = 0; j < 4; ++j) {
            long long t = ((long long)(q[c * 4 + j] - mean) * factor) >> 1;
            int v2 = (int)t + lnbi[o0 + j];
            float h = (float)v2 * sfo[o0 + j];
            lmn = fminf(lmn, h);
            lmx = fmaxf(lmx, h);
        }
    }
    #pragma unroll
    for (int off = 32; off; off >>= 1) {
        lmn = fminf(lmn, __shfl_xor(lmn, off));
        lmx = fmaxf(lmx, __shfl_xor(lmx, off));
    }
    if (lane == 0) { fmn[wave] = lmn; fmx[wave] = lmx; }
    __syncthreads();
    if (tid == 0) {
        float mn = fminf(fminf(fmn[0], fmn[1]), fminf(fmn[2], fmn[3]));
        float mx = fmaxf(fmaxf(fmx[0], fmx[1]), fmaxf(fmx[2], fmx[3]));
        volatile unsigned* sc = (volatile unsigned*)(ws + SC_OFF);
        unsigned emn = fenc(mn), emx = fenc(mx);
        if (emn < sc[2]) atomicMin((unsigned*)&sc[2], emn);   // guarded, 1/block
        if (emx > sc[3]) atomicMax((unsigned*)&sc[3], emx);
    }
}

// ============ K5: finalize s2 + frexp tables ============
__global__ __launch_bounds__(256) void k5_scale2(char* __restrict__ ws) {
    __shared__ float s_sh;
    unsigned* sc = (unsigned*)(ws + SC_OFF);
    if (threadIdx.x == 0) {
        float mn = fdec(sc[2]), mx = fdec(sc[3]);
        float s2 = fmaxf(fmaxf(fabsf(mn), fabsf(mx)), 1e-8f) / 127.0f;
        ((float*)sc)[6] = s2;
        s_sh = s2;
    }
    __syncthreads();
    float s2 = s_sh;
    const float* sfo = (const float*)(ws + SFO_OFF);
    double* rs2 = (double*)(ws + RS2_OFF);
    for (int o = threadIdx.x; o < HDIM; o += 256) {
        double r = (double)sfo[o] / (double)s2;
        int ex; double mant = frexp(r, &ex);
        double m = floor(mant * 2147483648.0 + 0.5);
        rs2[o] = m * exp2((double)(ex - 31));
    }
}

// ============ K6: block-per-row: recompute q -> y2 -> 8-bit requant, in-place out ============
__global__ __launch_bounds__(192) void k6_out(char* __restrict__ ws, float* __restrict__ out) {
    int row = blockIdx.x, tid = threadIdx.x;
    size_t base = (size_t)row * HDIM;
    const int* buf = (const int*)out;   // acc lives in d_out; read-before-write per thread
    const double* rs1 = (const double*)(ws + RS1_OFF);
    const double* rs2 = (const double*)(ws + RS2_OFF);
    double rsm1 = *(const double*)(ws + RSM1_OFF);
    int mean = ((const int*)(ws + MEAN_OFF))[row];
    long long factor = ((const long long*)(ws + FACT_OFF))[row];
    float s2 = ((const float*)(ws + SC_OFF))[6];
    const int* lnbi = (const int*)(ws + LNBI_OFF);
    int4 a = ((const int4*)(buf + base))[tid];
    int w4 = ((const int*)(ws + WX_OFF + base))[tid];
    int o0 = tid * 4;
    int q[4];
    computeQ(a, w4, o0, rs1, rsm1, q);
    float4 r;
    float* rp = &r.x;
    #pragma unroll
    for (int j = 0; j < 4; ++j) {
        long long t = ((long long)(q[j] - mean) * factor) >> 1;   // floor(y*factor/2)
        int v2 = (int)t + lnbi[o0 + j];
        double qq = rint((double)v2 * rs2[o0 + j]);
        qq = fmin(fmax(qq, -128.0), 127.0);
        rp[j] = (float)qq * s2;
    }
    ((float4*)(out + base))[tid] = r;
    if (row == 0 && tid == 0) out[(size_t)NTOK * HDIM] = s2;
}

extern "C" void kernel_launch(void* const* d_in, const int* in_sizes, int n_in,
                              void* d_out, int out_size, void* d_ws, size_t ws_size,
                              hipStream_t stream) {
    const float* hs   = (const float*)d_in[0];
    const float* phsf = (const float*)d_in[1];
    const float* inp  = (const float*)d_in[2];
    const float* pisf = (const float*)d_in[3];
    const float* W    = (const float*)d_in[4];
    const float* bias = (const float*)d_in[5];
    const float* ln_w = (const float*)d_in[6];
    const float* ln_b = (const float*)d_in[7];
    char* ws = (char*)d_ws;
    float* out = (float*)d_out;
    int* buf = (int*)d_out;   // d_out doubles as the 100MB int32 acc buffer

    k0_prep<<<HDIM, 256, 0, stream>>>(W, bias, ln_w, ln_b, phsf, ws);
    k1_gemm<<<(NTOK / 64) * 6, 256, 0, stream>>>(hs, inp, phsf, pisf, ws, buf);
    k2_scale1<<<1, 256, 0, stream>>>(pisf, ws);
    k3_rows<<<NTOK / 4, 256, 0, stream>>>(ws, buf);
    k4_rows<<<NTOK / 4, 256, 0, stream>>>(ws, buf);
    k5_scale2<<<1, 256, 0, stream>>>(ws);
    k6_out<<<NTOK, 192, 0, stream>>>(ws, out);
}

// Round 6
// 538.945 us; speedup vs baseline: 1.2328x; 1.2328x over previous
//
#include <hip/hip_runtime.h>

typedef int i32x4 __attribute__((ext_vector_type(4)));

#define HDIM 768
#define NTOK 32768
#define BKI 64
#define NKT (HDIM / BKI)   // 12

// ---- workspace layout (bytes) ----
static constexpr size_t WX_OFF   = 0;                    // int8 [NTOK*HDIM] = 25165824
static constexpr size_t W8_OFF   = 25165824;             // int8 [768*768] = 589824
static constexpr size_t RS1_OFF  = W8_OFF + 589824;      // double[768]
static constexpr size_t RS2_OFF  = RS1_OFF + 6144;       // double[768]
static constexpr size_t BS_OFF   = RS2_OFF + 6144;       // float [768] bias_scale
static constexpr size_t BINT_OFF = BS_OFF + 3072;        // int   [768] b_int
static constexpr size_t LNBI_OFF = BINT_OFF + 3072;      // int   [768] LN bias_int
static constexpr size_t SFO_OFF  = LNBI_OFF + 3072;      // float [768] sf_out
static constexpr size_t SC_OFF   = SFO_OFF + 3072;       // 16 words: [0]min1 [1]max1 [2]min2 [3]max2 [5]s [6]s2 [8..9]maxvar(ull)
static constexpr size_t MAXV_OFF = SC_OFF + 32;          // ull max var0
static constexpr size_t RSM1_OFF = SC_OFF + 64;          // double rs_m1
static constexpr size_t MEAN_OFF = RSM1_OFF + 64;        // int  [NTOK]
static constexpr size_t FACT_OFF = MEAN_OFF + 131072;    // ll   [NTOK]

// sortable-uint encoding of float for atomic min/max
__device__ __forceinline__ unsigned fenc(float f) {
    unsigned u = __float_as_uint(f);
    return (u >> 31) ? ~u : (u | 0x80000000u);
}
__device__ __forceinline__ float fdec(unsigned e) {
    unsigned u = (e >> 31) ? (e & 0x7fffffffu) : ~e;
    return __uint_as_float(u);
}

// async global->LDS, 16B/lane; global addr per-lane, LDS dest wave-uniform+lane*16
#define GLDS16(g, l) __builtin_amdgcn_global_load_lds( \
    (const __attribute__((address_space(1))) unsigned int*)(g), \
    (__attribute__((address_space(3))) unsigned int*)(l), 16, 0, 0)

__device__ __forceinline__ int pack4(float4 v, float s) {
    int x0 = (int)rintf(v.x * s) & 255;
    int x1 = (int)rintf(v.y * s) & 255;
    int x2 = (int)rintf(v.z * s) & 255;
    int x3 = (int)rintf(v.w * s) & 255;
    return x0 | (x1 << 8) | (x2 << 16) | (x3 << 24);
}

// ============ K0: weight quantization (int8) + per-channel tables + scalar init ============
__global__ __launch_bounds__(256) void k0_prep(const float* __restrict__ W,
                                               const float* __restrict__ bias,
                                               const float* __restrict__ ln_w,
                                               const float* __restrict__ ln_b,
                                               const float* __restrict__ phsf,
                                               char* __restrict__ ws) {
    int o = blockIdx.x, tid = threadIdx.x;
    __shared__ float red[256];
    __shared__ float fc_sh;
    float m = 0.f;
    for (int j = tid; j < HDIM; j += 256) m = fmaxf(m, fabsf(W[(size_t)o * HDIM + j]));
    red[tid] = m;
    __syncthreads();
    for (int s = 128; s; s >>= 1) { if (tid < s) red[tid] = fmaxf(red[tid], red[tid + s]); __syncthreads(); }
    if (tid == 0) {
        float fc = fmaxf(red[0], 1e-8f) / 127.0f;     // _sym_scale(8,...)
        float hsf = *phsf;
        float bs = fc * hsf;
        fc_sh = fc;
        ((float*)(ws + BS_OFF))[o] = bs;
        ((int*)(ws + BINT_OFF))[o] = (int)rintf(bias[o] / bs);   // _sym_quant(bias,32)
        float sf = sqrtf(768.0f) / 1073741824.0f;                // sqrt(H)/2^30
        float lw = ln_w[o], lb = ln_b[o];
        ((int*)(ws + LNBI_OFF))[o] = (int)floorf((lb / lw) / sf);
        ((float*)(ws + SFO_OFF))[o] = sf * lw;
    }
    __syncthreads();
    float fc = fc_sh;
    char* w8 = (char*)(ws + W8_OFF);
    for (int j = tid; j < HDIM; j += 256) {
        float q = rintf(W[(size_t)o * HDIM + j] / fc);
        q = fminf(fmaxf(q, -127.f), 126.f);           // clip [-n, n-1]
        w8[(size_t)o * HDIM + j] = (char)q;
    }
    if (blockIdx.x == 0 && tid < 16) {
        unsigned* sc = (unsigned*)(ws + SC_OFF);
        unsigned v = 0u;
        if (tid == 0 || tid == 2) v = 0xFFFFFFFFu;    // min slots
        sc[tid] = v;                                   // max slots + maxvar -> 0
    }
}

// ============ K1: tiled int8 GEMM (exact, i8 MFMA), double-buffered LDS, BK=64 ============
// BM=BN=128; grid 1536, XCD-pinned so 6 ntile-blocks of an mtile share one L2.
// B staged by GLDS (XOR swizzle: full-line global gathers, 2-way-free b64 frags);
// A staged f32 -> packed i8 through VGPRs. 12 K-iters (half the barriers of BK=32).
__global__ __launch_bounds__(256) void k1_gemm(const float* __restrict__ hs_in,
                                               const float* __restrict__ inp,
                                               const float* __restrict__ phsf,
                                               const float* __restrict__ pisf,
                                               char* __restrict__ ws,
                                               int* __restrict__ accOut) {
    __shared__ char As[2][128][80];     // stride 80: 2-way-max banks for b64 frags
    __shared__ char Bs[2][8192];        // 512 chunks x 16B, swizzled
    __shared__ float rmn[4], rmx[4];
    int tid = threadIdx.x, lane = tid & 63, wave = tid >> 6;
    int wrow = lane & 15, wkg = lane >> 4;
    int bid = blockIdx.x;
    int xcd = bid & 7, slot = bid >> 3;       // 8 XCDs x 192 slots
    int mtile = xcd * 32 + slot / 6;
    int ntile = slot % 6;
    int t0 = mtile * 128, o0 = ntile * 128;
    float inv_hsf = 1.0f / *phsf;
    float inv_isf = 1.0f / *pisf;
    const char* w8 = (const char*)(ws + W8_OFF);

    // B glds: chunk c -> row = c>>2, lds sub = c&3, global sub = (c&3) ^ ((row>>1)&3)
    int c1 = 256 + tid;
    int br0 = tid >> 2, bg0 = (tid & 3) ^ ((br0 >> 1) & 3);
    int br1 = c1 >> 2,  bg1 = (c1 & 3) ^ ((br1 >> 1) & 3);
    const char* bsrc0 = w8 + (size_t)(o0 + br0) * HDIM + bg0 * 16;
    const char* bsrc1 = w8 + (size_t)(o0 + br1) * HDIM + bg1 * 16;
    int bofs0 = wave * 1024, bofs1 = 4096 + wave * 1024;   // bytes (wave-uniform)

    // A staging: c = i*256+tid; row = c>>4, col = c&15 (float4 units, 16/row)
    int arow[8], acol[8];
    #pragma unroll
    for (int i = 0; i < 8; ++i) { int c = i * 256 + tid; arow[i] = c >> 4; acol[i] = c & 15; }

    // prologue: stage tile 0
    GLDS16(bsrc0, &Bs[0][bofs0]);
    GLDS16(bsrc1, &Bs[0][bofs1]);
    #pragma unroll
    for (int i = 0; i < 8; ++i) {
        float4 v = *(const float4*)(hs_in + (size_t)(t0 + arow[i]) * HDIM + acol[i] * 4);
        *(int*)&As[0][arow[i]][acol[i] * 4] = pack4(v, inv_hsf);
    }
    __syncthreads();

    int wm = wave & 1, wn = wave >> 1;
    i32x4 acc[4][4] = {};
    for (int kt = 0; kt < NKT; ++kt) {
        int cur = kt & 1, nxt = 1 - cur;
        float4 av[8];
        if (kt < NKT - 1) {
            GLDS16(bsrc0 + (kt + 1) * BKI, &Bs[nxt][bofs0]);
            GLDS16(bsrc1 + (kt + 1) * BKI, &Bs[nxt][bofs1]);
            #pragma unroll
            for (int i = 0; i < 8; ++i)
                av[i] = *(const float4*)(hs_in + (size_t)(t0 + arow[i]) * HDIM + (kt + 1) * BKI + acol[i] * 4);
        }
        long af[4][2], bf[4][2];
        #pragma unroll
        for (int mi = 0; mi < 4; ++mi) {
            int ra = wm * 64 + mi * 16 + wrow;
            #pragma unroll
            for (int kc = 0; kc < 2; ++kc)
                af[mi][kc] = *(const long*)&As[cur][ra][kc * 32 + wkg * 8];
        }
        #pragma unroll
        for (int nf = 0; nf < 4; ++nf) {
            int rb = wn * 64 + nf * 16 + wrow;
            #pragma unroll
            for (int kc = 0; kc < 2; ++kc) {
                int sub = (kc * 2 + (wkg >> 1)) ^ ((rb >> 1) & 3);
                bf[nf][kc] = *(const long*)&Bs[cur][(rb * 4 + sub) * 16 + (wkg & 1) * 8];
            }
        }
        #pragma unroll
        for (int kc = 0; kc < 2; ++kc)
            #pragma unroll
            for (int mi = 0; mi < 4; ++mi)
                #pragma unroll
                for (int nf = 0; nf < 4; ++nf)
                    acc[mi][nf] = __builtin_amdgcn_mfma_i32_16x16x32_i8(af[mi][kc], bf[nf][kc], acc[mi][nf], 0, 0, 0);
        if (kt < NKT - 1) {
            #pragma unroll
            for (int i = 0; i < 8; ++i)
                *(int*)&As[nxt][arow[i]][acol[i] * 4] = pack4(av[i], inv_hsf);
            __syncthreads();   // drains glds (vmcnt) + lds writes for nxt
        }
    }

    // epilogue: bias add (int), store acc, x_act min/max, wx store
    const float* bscale = (const float*)(ws + BS_OFF);
    const int* bint = (const int*)(ws + BINT_OFF);
    char* wx = (char*)(ws + WX_OFF);
    float lmn = 3.402823466e38f, lmx = -3.402823466e38f;
    #pragma unroll
    for (int mi = 0; mi < 4; ++mi)
        #pragma unroll
        for (int nf = 0; nf < 4; ++nf) {
            int o = o0 + wn * 64 + nf * 16 + wrow;
            int bi = bint[o];
            float bsc = bscale[o];
            #pragma unroll
            for (int r = 0; r < 4; ++r) {
                int t = t0 + wm * 64 + mi * 16 + wkg * 4 + r;
                int a = acc[mi][nf][r] + bi;
                size_t idx = (size_t)t * HDIM + o;
                accOut[idx] = a;
                float xin = inp[idx];
                float xa = (float)a * bsc + xin;
                lmn = fminf(lmn, xa);
                lmx = fmaxf(lmx, xa);
                wx[idx] = (char)rintf(xin * inv_isf);
            }
        }
    #pragma unroll
    for (int off = 32; off; off >>= 1) {
        lmn = fminf(lmn, __shfl_down(lmn, off));
        lmx = fmaxf(lmx, __shfl_down(lmx, off));
    }
    if (lane == 0) { rmn[wave] = lmn; rmx[wave] = lmx; }
    __syncthreads();
    if (tid == 0) {
        float mn = fminf(fminf(rmn[0], rmn[1]), fminf(rmn[2], rmn[3]));
        float mx = fmaxf(fmaxf(rmx[0], rmx[1]), fmaxf(rmx[2], rmx[3]));
        volatile unsigned* sc = (volatile unsigned*)(ws + SC_OFF);
        unsigned emn = fenc(mn), emx = fenc(mx);
        if (emn < sc[0]) atomicMin((unsigned*)&sc[0], emn);   // guarded, monotone
        if (emx > sc[1]) atomicMax((unsigned*)&sc[1], emx);
    }
}

// ============ K2: finalize ln_in_scale s + frexp tables ============
__global__ __launch_bounds__(256) void k2_scale1(const float* __restrict__ pisf, char* __restrict__ ws) {
    __shared__ float s_sh;
    unsigned* sc = (unsigned*)(ws + SC_OFF);
    if (threadIdx.x == 0) {
        float mn = fdec(sc[0]), mx = fdec(sc[1]);
        float s = fmaxf(fmaxf(fabsf(mn), fabsf(mx)), 1e-8f) / 2097151.0f;  // n = 2^21-1
        ((float*)sc)[5] = s;
        s_sh = s;
        double r = (double)(*pisf) / (double)s;
        int ex; double mant = frexp(r, &ex);
        double m1 = floor(mant * 2147483648.0 + 0.5);
        ((double*)(ws + RSM1_OFF))[0] = m1 * exp2((double)(ex - 31));
    }
    __syncthreads();
    float s = s_sh;
    const float* bs = (const float*)(ws + BS_OFF);
    double* rs1 = (double*)(ws + RS1_OFF);
    for (int o = threadIdx.x; o < HDIM; o += 256) {
        double r = (double)bs[o] / (double)s;
        int ex; double mant = frexp(r, &ex);
        double m = floor(mant * 2147483648.0 + 0.5);
        rs1[o] = m * exp2((double)(ex - 31));
    }
}

// shared q-recompute: exact f64 single-rounding fixed-point requant
__device__ __forceinline__ void computeQ(const int4& a, int w4, int o0,
                                         const double* rs1, double rsm1, int* q) {
    int av[4] = {a.x, a.y, a.z, a.w};
    #pragma unroll
    for (int j = 0; j < 4; ++j) {
        double q1 = rint((double)av[j] * rs1[o0 + j]);
        int wxj = (int)(char)(w4 >> (8 * j));
        double qq = q1 + rint((double)wxj * rsm1);
        qq = fmin(fmax(qq, -2097152.0), 2097151.0);   // clip [-2^21, 2^21-1]
        q[j] = (int)qq;
    }
}

// ============ K3: wave-per-row stats (mean + atomicMax var0) ============
// shift = ceil(0.5*log2(max_r var0_r)-16): monotone => max var0 suffices.
__global__ __launch_bounds__(256) void k3_rows(char* __restrict__ ws, const int* __restrict__ buf) {
    __shared__ unsigned long long vsh[4];
    int tid = threadIdx.x, lane = tid & 63, wave = tid >> 6;
    int row = blockIdx.x * 4 + wave;
    size_t base = (size_t)row * HDIM;
    const double* rs1 = (const double*)(ws + RS1_OFF);
    double rsm1 = *(const double*)(ws + RSM1_OFF);
    int q[12];
    int sum = 0;
    #pragma unroll
    for (int c = 0; c < 3; ++c) {
        int4 a = ((const int4*)(buf + base))[lane + 64 * c];
        int w4 = ((const int*)(ws + WX_OFF + base))[lane + 64 * c];
        computeQ(a, w4, (lane + 64 * c) * 4, rs1, rsm1, &q[c * 4]);
        sum += q[c * 4] + q[c * 4 + 1] + q[c * 4 + 2] + q[c * 4 + 3];
    }
    #pragma unroll
    for (int off = 32; off; off >>= 1) sum += __shfl_xor(sum, off);
    int mean = (int)rint((double)sum / 768.0);
    long long var0 = 0;
    #pragma unroll
    for (int k = 0; k < 12; ++k) { int y = q[k] - mean; var0 += (long long)y * (long long)y; }
    #pragma unroll
    for (int off = 32; off; off >>= 1) var0 += __shfl_xor(var0, off);
    if (lane == 0) {
        ((int*)(ws + MEAN_OFF))[row] = mean;
        vsh[wave] = (unsigned long long)var0;
    }
    __syncthreads();
    if (tid == 0) {
        unsigned long long v = max(max(vsh[0], vsh[1]), max(vsh[2], vsh[3]));
        unsigned long long* vp = (unsigned long long*)(ws + MAXV_OFF);
        if (v > *(volatile unsigned long long*)vp) atomicMax(vp, v);   // guarded, monotone
    }
}

// ============ K4: wave-per-row: recompute q, var@shift, factor, hs min/max ============
__global__ __launch_bounds__(256) void k4_rows(char* __restrict__ ws, const int* __restrict__ buf) {
    __shared__ float fmn[4], fmx[4];
    int tid = threadIdx.x, lane = tid & 63, wave = tid >> 6;
    int row = blockIdx.x * 4 + wave;
    size_t base = (size_t)row * HDIM;
    const double* rs1 = (const double*)(ws + RS1_OFF);
    double rsm1 = *(const double*)(ws + RSM1_OFF);
    unsigned long long maxv = *(const unsigned long long*)(ws + MAXV_OFF);
    double vmax = (double)(maxv < 1ULL ? 1ULL : maxv);
    int shift = (int)ceil(0.5 * log2(vmax) - 16.0);
    if (shift < 0) shift = 0;
    int mean = ((const int*)(ws + MEAN_OFF))[row];
    const int* lnbi = (const int*)(ws + LNBI_OFF);
    const float* sfo = (const float*)(ws + SFO_OFF);
    int q[12];
    #pragma unroll
    for (int c = 0; c < 3; ++c) {
        int4 a = ((const int4*)(buf + base))[lane + 64 * c];
        int w4 = ((const int*)(ws + WX_OFF + base))[lane + 64 * c];
        computeQ(a, w4, (lane + 64 * c) * 4, rs1, rsm1, &q[c * 4]);
    }
    long long var = 0;
    #pragma unroll
    for (int k = 0; k < 12; ++k) { int ysh = (q[k] - mean) >> shift; var += (long long)ysh * (long long)ysh; }
    #pragma unroll
    for (int off = 32; off; off >>= 1) var += __shfl_xor(var, off);
    double std_int = floor(sqrt((double)var)) * (double)(1LL << shift);
    if (std_int < 1.0) std_int = 1.0;
    long long factor = (long long)floor(2147483648.0 / std_int);
    if (lane == 0) ((long long*)(ws + FACT_OFF))[row] = factor;
    float lmn = 3.402823466e38f, lmx = -3.402823466e38f;
    #pragma unroll
    for (int c = 0; c < 3; ++c) {
        int o0 = (lane + 64 * c) * 4;
        #pragma unroll
        for (int j = 0; j < 4; ++j) {
            long long t = ((long long)(q[c * 4 + j] - mean) * factor) >> 1;
            int v2 = (int)t + lnbi[o0 + j];
            float h = (float)v2 * sfo[o0 + j];
            lmn = fminf(lmn, h);
            lmx = fmaxf(lmx, h);
        }
    }
    #pragma unroll
    for (int off = 32; off; off >>= 1) {
        lmn = fminf(lmn, __shfl_xor(lmn, off));
        lmx = fmaxf(lmx, __shfl_xor(lmx, off));
    }
    if (lane == 0) { fmn[wave] = lmn; fmx[wave] = lmx; }
    __syncthreads();
    if (tid == 0) {
        float mn = fminf(fminf(fmn[0], fmn[1]), fminf(fmn[2], fmn[3]));
        float mx = fmaxf(fmaxf(fmx[0], fmx[1]), fmaxf(fmx[2], fmx[3]));
        volatile unsigned* sc = (volatile unsigned*)(ws + SC_OFF);
        unsigned emn = fenc(mn), emx = fenc(mx);
        if (emn < sc[2]) atomicMin((unsigned*)&sc[2], emn);   // guarded, 1/block
        if (emx > sc[3]) atomicMax((unsigned*)&sc[3], emx);
    }
}

// ============ K5: finalize s2 + frexp tables ============
__global__ __launch_bounds__(256) void k5_scale2(char* __restrict__ ws) {
    __shared__ float s_sh;
    unsigned* sc = (unsigned*)(ws + SC_OFF);
    if (threadIdx.x == 0) {
        float mn = fdec(sc[2]), mx = fdec(sc[3]);
        float s2 = fmaxf(fmaxf(fabsf(mn), fabsf(mx)), 1e-8f) / 127.0f;
        ((float*)sc)[6] = s2;
        s_sh = s2;
    }
    __syncthreads();
    float s2 = s_sh;
    const float* sfo = (const float*)(ws + SFO_OFF);
    double* rs2 = (double*)(ws + RS2_OFF);
    for (int o = threadIdx.x; o < HDIM; o += 256) {
        double r = (double)sfo[o] / (double)s2;
        int ex; double mant = frexp(r, &ex);
        double m = floor(mant * 2147483648.0 + 0.5);
        rs2[o] = m * exp2((double)(ex - 31));
    }
}

// ============ K6: flat streaming: recompute q -> y2 -> 8-bit requant, in-place ============
__global__ __launch_bounds__(256) void k6_out(char* __restrict__ ws, float* __restrict__ out) {
    int idx4 = blockIdx.x * 256 + threadIdx.x;    // one int4 per thread, 6.29M total
    int row = idx4 / 192;                          // 192 int4s per row
    int o0 = (idx4 - row * 192) * 4;
    const int* buf = (const int*)out;
    const double* rs1 = (const double*)(ws + RS1_OFF);
    const double* rs2 = (const double*)(ws + RS2_OFF);
    double rsm1 = *(const double*)(ws + RSM1_OFF);
    int mean = ((const int*)(ws + MEAN_OFF))[row];
    long long factor = ((const long long*)(ws + FACT_OFF))[row];
    float s2 = ((const float*)(ws + SC_OFF))[6];
    const int* lnbi = (const int*)(ws + LNBI_OFF);
    int4 a = ((const int4*)buf)[idx4];
    int w4 = ((const int*)(ws + WX_OFF))[idx4];
    int q[4];
    computeQ(a, w4, o0, rs1, rsm1, q);
    float4 r;
    float* rp = &r.x;
    #pragma unroll
    for (int j = 0; j < 4; ++j) {
        long long t = ((long long)(q[j] - mean) * factor) >> 1;   // floor(y*factor/2)
        int v2 = (int)t + lnbi[o0 + j];
        double qq = rint((double)v2 * rs2[o0 + j]);
        qq = fmin(fmax(qq, -128.0), 127.0);
        rp[j] = (float)qq * s2;
    }
    ((float4*)out)[idx4] = r;
    if (idx4 == 0) out[(size_t)NTOK * HDIM] = s2;
}

extern "C" void kernel_launch(void* const* d_in, const int* in_sizes, int n_in,
                              void* d_out, int out_size, void* d_ws, size_t ws_size,
                              hipStream_t stream) {
    const float* hs   = (const float*)d_in[0];
    const float* phsf = (const float*)d_in[1];
    const float* inp  = (const float*)d_in[2];
    const float* pisf = (const float*)d_in[3];
    const float* W    = (const float*)d_in[4];
    const float* bias = (const float*)d_in[5];
    const float* ln_w = (const float*)d_in[6];
    const float* ln_b = (const float*)d_in[7];
    char* ws = (char*)d_ws;
    float* out = (float*)d_out;
    int* buf = (int*)d_out;   // d_out doubles as the 100MB int32 acc buffer

    k0_prep<<<HDIM, 256, 0, stream>>>(W, bias, ln_w, ln_b, phsf, ws);
    k1_gemm<<<(NTOK / 128) * 6, 256, 0, stream>>>(hs, inp, phsf, pisf, ws, buf);
    k2_scale1<<<1, 256, 0, stream>>>(pisf, ws);
    k3_rows<<<NTOK / 4, 256, 0, stream>>>(ws, buf);
    k4_rows<<<NTOK / 4, 256, 0, stream>>>(ws, buf);
    k5_scale2<<<1, 256, 0, stream>>>(ws);
    k6_out<<<NTOK * HDIM / 1024, 256, 0, stream>>>(ws, out);
}